// Round 20
// baseline (364.601 us; speedup 1.0000x reference)
//
#include <hip/hip_runtime.h>
#include <hip/hip_bf16.h>
#include <math.h>

#define L_SEQ 16384
#define DM 256
#define DI 512
#define DS 16
#define NCH 512   // number of scan chunks
#define CHL 32    // chunk length (NCH*CHL == L_SEQ)
#define CLB 16    // conv: timesteps per thread

typedef __attribute__((ext_vector_type(8))) short short8v;
typedef __attribute__((ext_vector_type(4))) float f32x4;

__device__ __forceinline__ float tanh_fast(float x){
  float xc = fminf(x, 15.f);
  float t = __expf(2.f*xc);
  return (t-1.f)/(t+1.f);
}
__device__ __forceinline__ float gelu_f(float x){
  float x3 = x*x*x;
  return 0.5f*x*(1.0f + tanh_fast(0.7978845608028654f*(x + 0.044715f*x3)));
}
__device__ __forceinline__ float silu_f(float x){
  return x / (1.0f + __expf(-x));
}
__device__ __forceinline__ float softplus_f(float x){
  return fmaxf(x,0.0f) + __logf(1.0f + __expf(-fabsf(x)));
}
__device__ __forceinline__ float bf2f(unsigned short u){
  return __uint_as_float(((unsigned int)u)<<16);
}
__device__ __forceinline__ void gload16(const void* g, void* l){
  __builtin_amdgcn_global_load_lds((const __attribute__((address_space(1))) void*)g,
                                   (__attribute__((address_space(3))) void*)l, 16, 0, 0);
}

// r^(n+1) for n=0..15, ~16 muls, depth ~4 (replaces 16 quarter-rate exps)
__device__ __forceinline__ void powers16(float r, float* dA){
  float r2 = r*r;
  float r4 = r2*r2;
  float r8 = r4*r4;
  dA[0]=r;        dA[1]=r2;       dA[2]=r2*r;     dA[3]=r4;
  dA[4]=r4*r;     dA[5]=r4*r2;    dA[6]=r4*dA[2]; dA[7]=r8;
  dA[8]=r8*r;     dA[9]=r8*r2;    dA[10]=r8*dA[2];dA[11]=r8*r4;
  dA[12]=r8*dA[4];dA[13]=r8*dA[5];dA[14]=r8*dA[6];dA[15]=r8*r8;
}

// ---- merged weight prep (rmsw->inWt, ln2g->W1t) + zeros + MLP par table.
//      pars: [0:128) gW1s  [128:256) bW1s+b1  [256:384) ln3g  [384:512) ln3b
//            [512:640) W2  [640] b2 ----
__global__ void k_prep(const float* __restrict__ inW, const float* __restrict__ rmsw,
                       const float* __restrict__ outW, const float* __restrict__ W1,
                       const float* __restrict__ xpW, const float* __restrict__ dtW,
                       const float* __restrict__ ln2g, const float* __restrict__ ln2b,
                       const float* __restrict__ b1, const float* __restrict__ ln3g,
                       const float* __restrict__ ln3b, const float* __restrict__ W2,
                       const float* __restrict__ b2,
                       __hip_bfloat16* __restrict__ inWt, __hip_bfloat16* __restrict__ outWt,
                       __hip_bfloat16* __restrict__ W1t, __hip_bfloat16* __restrict__ Wdbc_t,
                       float* __restrict__ rowsq1, float* __restrict__ rowsum2,
                       float* __restrict__ rowsq2, float* __restrict__ pars){
  int idx = blockIdx.x*256 + threadIdx.x;
  if(idx < 524288){                      // inW: 2x[256][1024] -> [1024][256], rmsw fold
    int layer = idx >> 18;
    int r = idx & 262143;
    int n = r >> 8, k = r & 255;
    inWt[idx] = __float2bfloat16(inW[layer*262144 + k*1024 + n] * rmsw[layer*256+k]);
  } else if(idx < 786432){               // outW: 2x[512][256] -> [256][512]
    int j = idx - 524288;
    int layer = j >> 17;
    int r = j & 131071;
    int n = r >> 9, k = r & 511;
    outWt[j] = __float2bfloat16(outW[layer*131072 + k*256 + n]);
  } else if(idx < 819200){               // W1: [256][128] -> [128][256], ln2g fold
    int j = idx - 786432;
    int n = j >> 8, k = j & 255;
    W1t[j] = __float2bfloat16(W1[k*128 + n] * ln2g[k]);
  } else if(idx < 1474560){              // Wdbc: 2x[640][512]
    int j = idx - 819200;
    int layer = j / 327680;
    int r = j % 327680;
    int n = r >> 9, k = r & 511;
    const float* xp = xpW + layer*512*48;
    float v;
    if(n < 512){
      const float* dt = dtW + layer*16*512;
      float s = 0.f;
#pragma unroll
      for(int q=0;q<16;q++) s = fmaf(xp[k*48+q], dt[q*512+n], s);
      v = s;
    } else if(n < 544){
      v = xp[k*48 + 16 + (n-512)];
    } else v = 0.f;
    Wdbc_t[j] = __float2bfloat16(v);
  } else if(idx < 1490944){              // rowsq1 zero
    rowsq1[idx - 1474560] = 0.f;
  } else if(idx < 1507328){              // rowsum2 zero
    rowsum2[idx - 1490944] = 0.f;
  } else if(idx < 1523712){              // rowsq2 zero
    rowsq2[idx - 1507328] = 0.f;
  } else if(idx < 1524353){              // MLP par table
    int j = idx - 1523712;
    if(j < 128){
      float s = 0.f;
      for(int k=0;k<256;k++) s = fmaf(ln2g[k], W1[k*128+j], s);
      pars[j] = s;
    } else if(j < 256){
      int n = j - 128;
      float s = 0.f;
      for(int k=0;k<256;k++) s = fmaf(ln2b[k], W1[k*128+n], s);
      pars[j] = s + b1[n];
    } else if(j < 384) pars[j] = ln3g[j-256];
    else if(j < 512)   pars[j] = ln3b[j-384];
    else if(j < 640)   pars[j] = W2[j-512];
    else               pars[640] = b2[0];
  }
}

// ---- input projection + LN + gelu -> bf16 u; also rowsq0[r] = sum(u_r^2) ----
__global__ __launch_bounds__(256) void k_input(const float* __restrict__ x,
                        const float* __restrict__ Win, const float* __restrict__ bin,
                        const float* __restrict__ g, const float* __restrict__ b,
                        __hip_bfloat16* __restrict__ u, float* __restrict__ rowsq){
  int wv = threadIdx.x>>6, lane = threadIdx.x&63;
  int r = blockIdx.x*4 + wv;
  int c0 = lane*4;
  float acc[4];
  { float4 bv = *(const float4*)&bin[c0];
    acc[0]=bv.x; acc[1]=bv.y; acc[2]=bv.z; acc[3]=bv.w; }
#pragma unroll
  for(int k=0;k<32;k++){
    float xk = x[r*32+k];
    float4 wv4 = *(const float4*)&Win[k*DM+c0];
    acc[0]=fmaf(xk,wv4.x,acc[0]); acc[1]=fmaf(xk,wv4.y,acc[1]);
    acc[2]=fmaf(xk,wv4.z,acc[2]); acc[3]=fmaf(xk,wv4.w,acc[3]);
  }
  float s = (acc[0]+acc[1])+(acc[2]+acc[3]);
  float sq = acc[0]*acc[0]+acc[1]*acc[1]+acc[2]*acc[2]+acc[3]*acc[3];
#pragma unroll
  for(int o=32;o;o>>=1){ s += __shfl_xor(s,o); sq += __shfl_xor(sq,o); }
  float mean = s*(1.0f/DM);
  float var = sq*(1.0f/DM) - mean*mean;
  float rs = rsqrtf(var+1e-5f);
  float4 gv = *(const float4*)&g[c0];
  float4 bv = *(const float4*)&b[c0];
  float go[4];
  go[0] = gelu_f((acc[0]-mean)*rs*gv.x+bv.x);
  go[1] = gelu_f((acc[1]-mean)*rs*gv.y+bv.y);
  go[2] = gelu_f((acc[2]-mean)*rs*gv.z+bv.z);
  go[3] = gelu_f((acc[3]-mean)*rs*gv.w+bv.w);
  float ssq = go[0]*go[0]+go[1]*go[1]+go[2]*go[2]+go[3]*go[3];
#pragma unroll
  for(int o=32;o;o>>=1) ssq += __shfl_xor(ssq,o);
  if(lane==0) rowsq[r] = ssq;
  __hip_bfloat16 ob[4] = {__float2bfloat16(go[0]),__float2bfloat16(go[1]),
                          __float2bfloat16(go[2]),__float2bfloat16(go[3])};
  *(uint2*)&u[r*DM+c0] = *(uint2*)ob;
}

// ---- bf16 MFMA GEMM, 8 waves, BK=64 SINGLE-BUFFER (34KB LDS -> 4 blocks/CU,
//      TLP-hидden staging) + XCD remap + two-half LDS-staged coalesced epilogue.
//      EPI: 0=store, 1=+R, 4=delta|BC split, 5=+R+rowsq atomic,
//      6=row-scale rsqrt(rowsq/256+eps), 7=+R+rowsum&rowsq atomics,
//      8=MLP fused: LN2-folded gelu + LN3 + W2 dot + tanh -> C[row]. ----
template<int EPI, typename OT>
__global__ __launch_bounds__(512) void k_mgemm(const __hip_bfloat16* __restrict__ A,
    const __hip_bfloat16* __restrict__ Wt, const float* __restrict__ bias,
    const OT* __restrict__ R, OT* __restrict__ C, float* __restrict__ C2,
    float* __restrict__ rowsq, int M, int K, int ldc, int Nout){
  __shared__ char lds[33792];          // As 16K | Bs 16K ; epi: Ob[64][132] f32 overlays
  float* Ob = (float*)lds;
  int t = threadIdx.x, lane = t&63, wave = t>>6;   // 8 waves
  // XCD-aware tile remap (block f -> XCD f%8; XCD owns contiguous y-panels)
  int gx = gridDim.x;
  int f = blockIdx.y*gx + blockIdx.x;
  int s = f >> 3;
  int sy = s/gx;
  int yb = (f&7)*(gridDim.y>>3) + sy;
  int xb = s - sy*gx;
  int m0 = yb*128, n0 = xb*128;
  int wm = (wave>>1)*32, wn = (wave&1)*64;   // wave owns 32 rows x 64 cols
  f32x4 acc[2][4] = {};
  // staging descriptors (BK=64: 128B rows, 8-slot XOR swizzle)
  int soff[2], srow[2], scol[2];
#pragma unroll
  for(int c=0;c<2;c++){
    int off = c*8192 + t*16;
    int row = off>>7;
    int sl  = ((off>>4)&7) ^ (row&7);
    soff[c]=off; srow[c]=row; scol[c]=sl*8;
  }
  int nk = K >> 6;
  for(int ki=0; ki<nk; ki++){
    int kt = ki<<6;
    __syncthreads();                     // prior reads done before restage
#pragma unroll
    for(int c=0;c<2;c++){
      gload16(&A [(m0+srow[c])*K + kt + scol[c]], lds + soff[c]);
      gload16(&Wt[(n0+srow[c])*K + kt + scol[c]], lds + 16384 + soff[c]);
    }
    asm volatile("s_waitcnt vmcnt(0)" ::: "memory");
    __syncthreads();
    const short* As = (const short*)lds;
    const short* Bs = (const short*)(lds + 16384);
#pragma unroll
    for(int ks=0; ks<2; ks++){
      short8v a[2], b[4];
      int k8 = ks*4 + (lane>>4);
#pragma unroll
      for(int i=0;i<2;i++){
        int lr = wm + i*16 + (lane&15);
        a[i] = *(const short8v*)&As[lr*64 + (k8 ^ (lr&7))*8];
      }
#pragma unroll
      for(int j=0;j<4;j++){
        int lr = wn + j*16 + (lane&15);
        b[j] = *(const short8v*)&Bs[lr*64 + (k8 ^ (lr&7))*8];
      }
#pragma unroll
      for(int i=0;i<2;i++)
#pragma unroll
        for(int j=0;j<4;j++)
          acc[i][j] = __builtin_amdgcn_mfma_f32_16x16x32_bf16(a[i], b[j], acc[i][j], 0,0,0);
    }
  }
  // two-half epilogue: rows [h*64, h*64+64)
#pragma unroll
  for(int h=0; h<2; h++){
    __syncthreads();
    if((wm>>6)==h){
      int base = wm & 63;
#pragma unroll
      for(int i=0;i<2;i++)
#pragma unroll
        for(int j=0;j<4;j++)
#pragma unroll
          for(int r=0;r<4;r++)
            Ob[(base + i*16 + (lane>>4)*4 + r)*132 + wn + j*16 + (lane&15)] = acc[i][j][r];
    }
    __syncthreads();
    if constexpr(EPI==8){
      // LN2-folded MLP + LN3 + W2 + tanh. 8 threads per row, 16 cols each.
      int rl = t>>3;
      int grow = m0 + h*64 + rl;
      int c0b = (t&7)*16;
      float mean = (float)R[grow]*(1.0f/DM);
      float var = rowsq[grow]*(1.0f/DM) - mean*mean;
      float rsv = rsqrtf(var+1e-5f);
      float hbuf[16];
      float s3=0.f, q3=0.f;
#pragma unroll
      for(int v=0;v<4;v++){
        float4 o = *(const float4*)&Ob[rl*132 + c0b + v*4];
        float oa[4] = {o.x,o.y,o.z,o.w};
#pragma unroll
        for(int j=0;j<4;j++){
          int col = c0b + v*4 + j;
          float val = rsv*oa[j] - rsv*mean*C2[col] + C2[128+col];
          float hh = gelu_f(val);
          hbuf[v*4+j] = hh;
          s3 += hh; q3 += hh*hh;
        }
      }
      s3 += __shfl_xor(s3,1); q3 += __shfl_xor(q3,1);
      s3 += __shfl_xor(s3,2); q3 += __shfl_xor(q3,2);
      s3 += __shfl_xor(s3,4); q3 += __shfl_xor(q3,4);
      float m3 = s3*(1.0f/128), v3 = q3*(1.0f/128) - m3*m3;
      float rs3 = rsqrtf(v3+1e-5f);
      float dot = 0.f;
#pragma unroll
      for(int j=0;j<16;j++){
        int col = c0b + j;
        dot += ((hbuf[j]-m3)*rs3*C2[256+col] + C2[384+col]) * C2[512+col];
      }
      dot += __shfl_xor(dot,1); dot += __shfl_xor(dot,2); dot += __shfl_xor(dot,4);
      if((t&7)==0) C[grow] = tanh_fast(dot + C2[640]);
    } else {
      float ssq_acc = 0.f, ssum_acc = 0.f;
#pragma unroll
      for(int v=0; v<4; v++){
        int fidx = (t*4+v)*4;
        int row = fidx>>7, col = fidx&127;
        if(col < Nout){
          float4 o = *(const float4*)&Ob[row*132 + col];
          int grow = m0 + h*64 + row, gcol = n0 + col;
          if(EPI==1 || EPI==5 || EPI==7){
            if constexpr(sizeof(OT)==2){
              ushort4 rv = *(const ushort4*)&R[grow*ldc+gcol];
              o.x+=bf2f(rv.x); o.y+=bf2f(rv.y); o.z+=bf2f(rv.z); o.w+=bf2f(rv.w);
            } else {
              float4 rv = *(const float4*)&R[grow*ldc+gcol];
              o.x+=rv.x; o.y+=rv.y; o.z+=rv.z; o.w+=rv.w;
            }
            if(EPI==5 || EPI==7) ssq_acc += o.x*o.x + o.y*o.y + o.z*o.z + o.w*o.w;
            if(EPI==7) ssum_acc += o.x + o.y + o.z + o.w;
          }
          if(EPI==6){
            float rs = rsqrtf(rowsq[grow]*(1.0f/DM) + 1e-5f);
            o.x*=rs; o.y*=rs; o.z*=rs; o.w*=rs;
          }
          if(EPI==4){
            if(gcol < 512){
              float4 bv = *(const float4*)&bias[gcol];
              float4 so = {softplus_f(o.x+bv.x), softplus_f(o.y+bv.y),
                           softplus_f(o.z+bv.z), softplus_f(o.w+bv.w)};
              __hip_bfloat16 ob[4] = {__float2bfloat16(so.x),__float2bfloat16(so.y),
                                      __float2bfloat16(so.z),__float2bfloat16(so.w)};
              *(uint2*)&C[grow*ldc+gcol] = *(uint2*)ob;
            } else {
              *(float4*)&C2[grow*32 + (gcol-512)] = o;
            }
          } else {
            if constexpr(sizeof(OT)==2){
              __hip_bfloat16 ob[4] = {__float2bfloat16(o.x),__float2bfloat16(o.y),
                                      __float2bfloat16(o.z),__float2bfloat16(o.w)};
              *(uint2*)&C[grow*ldc+gcol] = *(uint2*)ob;
            } else {
              *(float4*)&C[grow*ldc+gcol] = o;
            }
          }
        }
      }
      if(EPI==5 || EPI==7){
        ssq_acc += __shfl_xor(ssq_acc,1);
        ssq_acc += __shfl_xor(ssq_acc,2);
        ssq_acc += __shfl_xor(ssq_acc,4);
        if((t&7)==0) atomicAdd(&rowsq[m0 + h*64 + (t>>3)], ssq_acc);
      }
      if(EPI==7){
        ssum_acc += __shfl_xor(ssum_acc,1);
        ssum_acc += __shfl_xor(ssum_acc,2);
        ssum_acc += __shfl_xor(ssum_acc,4);
        if((t&7)==0) atomicAdd(&C2[m0 + h*64 + (t>>3)], ssum_acc);
      }
    }
  }
}

// ---- causal depthwise conv (k=4) + bias + silu, sliding window. ----
__global__ __launch_bounds__(256) void k_conv(const __hip_bfloat16* __restrict__ xz,
                       const float* __restrict__ cw, const float* __restrict__ cb,
                       __hip_bfloat16* __restrict__ xs_bf){
  int idx = blockIdx.x*256 + threadIdx.x;   // (L_SEQ/CLB)*128 threads
  int cg = idx & 127, lb = idx >> 7;
  int c4 = cg*4;
  int l0 = lb*CLB;
  float w[4][4], bias[4];
#pragma unroll
  for(int j=0;j<4;j++){
    float4 wv = *(const float4*)&cw[(c4+j)*4];
    w[j][0]=wv.x; w[j][1]=wv.y; w[j][2]=wv.z; w[j][3]=wv.w;
  }
  { float4 bv = *(const float4*)&cb[c4];
    bias[0]=bv.x; bias[1]=bv.y; bias[2]=bv.z; bias[3]=bv.w; }
  float xm0[4], xm1[4], xm2[4];   // x[l-3], x[l-2], x[l-1]
#pragma unroll
  for(int j=0;j<4;j++){ xm0[j]=0.f; xm1[j]=0.f; xm2[j]=0.f; }
  if(l0 >= 3){
    ushort4 r0 = *(const ushort4*)&xz[(l0-3)*1024 + c4];
    ushort4 r1 = *(const ushort4*)&xz[(l0-2)*1024 + c4];
    ushort4 r2 = *(const ushort4*)&xz[(l0-1)*1024 + c4];
    xm0[0]=bf2f(r0.x); xm0[1]=bf2f(r0.y); xm0[2]=bf2f(r0.z); xm0[3]=bf2f(r0.w);
    xm1[0]=bf2f(r1.x); xm1[1]=bf2f(r1.y); xm1[2]=bf2f(r1.z); xm1[3]=bf2f(r1.w);
    xm2[0]=bf2f(r2.x); xm2[1]=bf2f(r2.y); xm2[2]=bf2f(r2.z); xm2[3]=bf2f(r2.w);
  }
#pragma unroll 4
  for(int l=l0; l<l0+CLB; l++){
    ushort4 rc = *(const ushort4*)&xz[l*1024 + c4];
    float xc[4] = {bf2f(rc.x), bf2f(rc.y), bf2f(rc.z), bf2f(rc.w)};
    __hip_bfloat16 ob[4];
#pragma unroll
    for(int j=0;j<4;j++){
      float acc = bias[j];
      acc = fmaf(xm0[j], w[j][0], acc);
      acc = fmaf(xm1[j], w[j][1], acc);
      acc = fmaf(xm2[j], w[j][2], acc);
      acc = fmaf(xc[j],  w[j][3], acc);
      ob[j] = __float2bfloat16(silu_f(acc));
    }
    *(uint2*)&xs_bf[l*DI + c4] = *(uint2*)ob;
#pragma unroll
    for(int j=0;j<4;j++){ xm0[j]=xm1[j]; xm1[j]=xm2[j]; xm2[j]=xc[j]; }
  }
}

// ---- scan phase 1: per-chunk (prod dA, local carry) per state -> bf16.
//      Fast path: A[n] == (n+1)*A[0] -> dA[n] = r^(n+1), r = exp(d*A[0]). ----
__global__ __launch_bounds__(256) void k_scan1(const __hip_bfloat16* __restrict__ delta,
                        const __hip_bfloat16* __restrict__ xs,
                        const float* __restrict__ dbc32, const float* __restrict__ A_log,
                        __hip_bfloat16* __restrict__ Atot, __hip_bfloat16* __restrict__ Btot){
  __shared__ float bcs[CHL*32];
  int t = threadIdx.x;
  int chunk = blockIdx.x >> 1;
  int e = ((blockIdx.x & 1) << 8) + t;
  int l0 = chunk*CHL;
  ((float4*)bcs)[t] = ((const float4*)&dbc32[l0*32])[t];
  float A[16];
  {
    const float4* al = (const float4*)&A_log[e*DS];
#pragma unroll
    for(int q=0;q<4;q++){
      float4 a = al[q];
      A[q*4+0] = -__expf(a.x); A[q*4+1] = -__expf(a.y);
      A[q*4+2] = -__expf(a.z); A[q*4+3] = -__expf(a.w);
    }
  }
  bool pf = true;
#pragma unroll
  for(int n=1;n<16;n++) pf = pf && (fabsf(A[n] - (n+1)*A[0]) <= 1e-4f*fabsf(A[n]));
  float carry[16], aprod[16];
#pragma unroll
  for(int n=0;n<16;n++){ carry[n]=0.f; aprod[n]=1.f; }
  __syncthreads();
  if(pf){
    float A0 = A[0];
#pragma unroll 2
    for(int li=0; li<CHL; li++){
      int l = l0 + li;
      float d  = bf2f(*(const unsigned short*)&delta[l*DI+e]);
      float xv = bf2f(*(const unsigned short*)&xs[l*DI+e]);
      float dxv = d*xv;
      const float4* bp = (const float4*)&bcs[li*32];
      float4 b0=bp[0], b1=bp[1], b2=bp[2], b3=bp[3];
      float B[16] = {b0.x,b0.y,b0.z,b0.w, b1.x,b1.y,b1.z,b1.w,
                     b2.x,b2.y,b2.z,b2.w, b3.x,b3.y,b3.z,b3.w};
      float r = __expf(d*A0);
      float dA[16]; powers16(r, dA);
#pragma unroll
      for(int n=0;n<16;n++){
        carry[n] = fmaf(carry[n], dA[n], dxv*B[n]);
        aprod[n] *= dA[n];
      }
    }
  } else {
#pragma unroll 2
    for(int li=0; li<CHL; li++){
      int l = l0 + li;
      float d  = bf2f(*(const unsigned short*)&delta[l*DI+e]);
      float xv = bf2f(*(const unsigned short*)&xs[l*DI+e]);
      float dxv = d*xv;
      const float4* bp = (const float4*)&bcs[li*32];
      float4 b0=bp[0], b1=bp[1], b2=bp[2], b3=bp[3];
      float B[16] = {b0.x,b0.y,b0.z,b0.w, b1.x,b1.y,b1.z,b1.w,
                     b2.x,b2.y,b2.z,b2.w, b3.x,b3.y,b3.z,b3.w};
#pragma unroll
      for(int n=0;n<16;n++){
        float dA = __expf(d*A[n]);
        carry[n] = fmaf(carry[n], dA, dxv*B[n]);
        aprod[n] *= dA;
      }
    }
  }
  __hip_bfloat16 apk[16], bpk[16];
#pragma unroll
  for(int n=0;n<16;n++){
    apk[n] = __float2bfloat16(aprod[n]);
    bpk[n] = __float2bfloat16(carry[n]);
  }
  uint4* ap = (uint4*)&Atot[chunk*8192 + e*DS];
  uint4* bp = (uint4*)&Btot[chunk*8192 + e*DS];
  ap[0] = ((const uint4*)apk)[0]; ap[1] = ((const uint4*)apk)[1];
  bp[0] = ((const uint4*)bpk)[0]; bp[1] = ((const uint4*)bpk)[1];
}

// ---- scan phase 2: carry-in per chunk (bf16 in/out), unroll-8 batched loads
//      (h0 aliases Btot: all batch loads precede batch stores). 128 blocks x 64. ----
__global__ __launch_bounds__(64) void k_scan2(const __hip_bfloat16* __restrict__ Atot,
                        const __hip_bfloat16* __restrict__ Btot,
                        __hip_bfloat16* __restrict__ h0){
  int tg = blockIdx.x*64 + threadIdx.x;
  float carry = 0.f;
  for(int c0=0;c0<NCH;c0+=8){
    float a[8], b[8];
#pragma unroll
    for(int j=0;j<8;j++){
      a[j] = bf2f(*(const unsigned short*)&Atot[(c0+j)*8192+tg]);
      b[j] = bf2f(*(const unsigned short*)&Btot[(c0+j)*8192+tg]);
    }
#pragma unroll
    for(int j=0;j<8;j++){
      h0[(c0+j)*8192+tg] = __float2bfloat16(carry);
      carry = fmaf(carry, a[j], b[j]);
    }
  }
}

// ---- scan phase 3: replay with bf16 carry-in, y = (sum h*C + xs*D)*silu(z) -> bf16 ----
__global__ __launch_bounds__(256) void k_scan3(const __hip_bfloat16* __restrict__ delta,
                        const __hip_bfloat16* __restrict__ xs,
                        const float* __restrict__ dbc32, const float* __restrict__ A_log,
                        const float* __restrict__ Dp, const __hip_bfloat16* __restrict__ h0,
                        const __hip_bfloat16* __restrict__ xz, __hip_bfloat16* __restrict__ y){
  __shared__ float bcs[CHL*32];
  int t = threadIdx.x;
  int chunk = blockIdx.x >> 1;
  int e = ((blockIdx.x & 1) << 8) + t;
  int l0 = chunk*CHL;
  ((float4*)bcs)[t] = ((const float4*)&dbc32[l0*32])[t];
  float A[16];
  {
    const float4* al = (const float4*)&A_log[e*DS];
#pragma unroll
    for(int q=0;q<4;q++){
      float4 a = al[q];
      A[q*4+0] = -__expf(a.x); A[q*4+1] = -__expf(a.y);
      A[q*4+2] = -__expf(a.z); A[q*4+3] = -__expf(a.w);
    }
  }
  bool pf = true;
#pragma unroll
  for(int n=1;n<16;n++) pf = pf && (fabsf(A[n] - (n+1)*A[0]) <= 1e-4f*fabsf(A[n]));
  float carry[16];
  {
    uint4 h0a = ((const uint4*)&h0[chunk*8192 + e*DS])[0];
    uint4 h0b = ((const uint4*)&h0[chunk*8192 + e*DS])[1];
    const unsigned short* hp = (const unsigned short*)&h0a;
#pragma unroll
    for(int n=0;n<8;n++) carry[n] = bf2f(hp[n]);
    const unsigned short* hq = (const unsigned short*)&h0b;
#pragma unroll
    for(int n=0;n<8;n++) carry[8+n] = bf2f(hq[n]);
  }
  float Dv = Dp[e];
  __syncthreads();
  if(pf){
    float A0 = A[0];
#pragma unroll 2
    for(int li=0; li<CHL; li++){
      int l = l0 + li;
      float d  = bf2f(*(const unsigned short*)&delta[l*DI+e]);
      float xv = bf2f(*(const unsigned short*)&xs[l*DI+e]);
      float dxv = d*xv;
      const float4* bp = (const float4*)&bcs[li*32];
      float4 b0=bp[0], b1=bp[1], b2=bp[2], b3=bp[3];
      float4 c0=bp[4], c1=bp[5], c2=bp[6], c3=bp[7];
      float B[16] = {b0.x,b0.y,b0.z,b0.w, b1.x,b1.y,b1.z,b1.w,
                     b2.x,b2.y,b2.z,b2.w, b3.x,b3.y,b3.z,b3.w};
      float Cv[16] = {c0.x,c0.y,c0.z,c0.w, c1.x,c1.y,c1.z,c1.w,
                      c2.x,c2.y,c2.z,c2.w, c3.x,c3.y,c3.z,c3.w};
      float r = __expf(d*A0);
      float dA[16]; powers16(r, dA);
      float p[4] = {0.f,0.f,0.f,0.f};
#pragma unroll
      for(int n=0;n<16;n++){
        carry[n] = fmaf(carry[n], dA[n], dxv*B[n]);
        p[n&3] = fmaf(carry[n], Cv[n], p[n&3]);
      }
      float ps = (p[0]+p[1]) + (p[2]+p[3]);
      float z = bf2f(*(const unsigned short*)&xz[l*1024 + 512 + e]);
      y[l*DI+e] = __float2bfloat16(fmaf(xv, Dv, ps) * silu_f(z));
    }
  } else {
#pragma unroll 2
    for(int li=0; li<CHL; li++){
      int l = l0 + li;
      float d  = bf2f(*(const unsigned short*)&delta[l*DI+e]);
      float xv = bf2f(*(const unsigned short*)&xs[l*DI+e]);
      float dxv = d*xv;
      const float4* bp = (const float4*)&bcs[li*32];
      float4 b0=bp[0], b1=bp[1], b2=bp[2], b3=bp[3];
      float4 c0=bp[4], c1=bp[5], c2=bp[6], c3=bp[7];
      float B[16] = {b0.x,b0.y,b0.z,b0.w, b1.x,b1.y,b1.z,b1.w,
                     b2.x,b2.y,b2.z,b2.w, b3.x,b3.y,b3.z,b3.w};
      float Cv[16] = {c0.x,c0.y,c0.z,c0.w, c1.x,c1.y,c1.z,c1.w,
                      c2.x,c2.y,c2.z,c2.w, c3.x,c3.y,c3.z,c3.w};
      float p[4] = {0.f,0.f,0.f,0.f};
#pragma unroll
      for(int n=0;n<16;n++){
        float dA = __expf(d*A[n]);
        carry[n] = fmaf(carry[n], dA, dxv*B[n]);
        p[n&3] = fmaf(carry[n], Cv[n], p[n&3]);
      }
      float ps = (p[0]+p[1]) + (p[2]+p[3]);
      float z = bf2f(*(const unsigned short*)&xz[l*1024 + 512 + e]);
      y[l*DI+e] = __float2bfloat16(fmaf(xv, Dv, ps) * silu_f(z));
    }
  }
}

extern "C" void kernel_launch(void* const* d_in, const int* in_sizes, int n_in,
                              void* d_out, int out_size, void* d_ws, size_t ws_size,
                              hipStream_t stream){
  const float* x    = (const float*)d_in[0];
  const float* Win  = (const float*)d_in[1];
  const float* bin  = (const float*)d_in[2];
  const float* ln1g = (const float*)d_in[3];
  const float* ln1b = (const float*)d_in[4];
  const float* rmsw = (const float*)d_in[5];
  const float* inW  = (const float*)d_in[6];
  const float* convW= (const float*)d_in[7];
  const float* convB= (const float*)d_in[8];
  const float* xpW  = (const float*)d_in[9];
  const float* dtW  = (const float*)d_in[10];
  const float* dtB  = (const float*)d_in[11];
  const float* A_log= (const float*)d_in[12];
  const float* Dp   = (const float*)d_in[13];
  const float* outW = (const float*)d_in[14];
  const float* ln2g = (const float*)d_in[15];
  const float* ln2b = (const float*)d_in[16];
  const float* W1   = (const float*)d_in[17];
  const float* b1   = (const float*)d_in[18];
  const float* ln3g = (const float*)d_in[19];
  const float* ln3b = (const float*)d_in[20];
  const float* W2   = (const float*)d_in[21];
  const float* b2   = (const float*)d_in[22];
  float* out = (float*)d_out;
  float* ws = (float*)d_ws;
  __hip_bfloat16* u_bf = (__hip_bfloat16*)ws;                 // 16384*256 bf16 (8MB)
  float* rowsq0  = ws + 4194304;                              // 16384 f32
  float* rowsq1  = ws + 4210688;                              // 16384 f32
  float* rowsum2 = ws + 4227072;                              // 16384 f32
  float* rowsq2  = ws + 4243456;                              // 16384 f32
  float* mlp_pars= ws + 4259840;                              // 641 f32
  __hip_bfloat16* xz_bf = (__hip_bfloat16*)(ws + 8388608);    // 16384*1024 bf16
  float* dbc32 = ws + 16777216;                               // 16384*32 f32
  __hip_bfloat16* delta_bf = (__hip_bfloat16*)(ws + 17301504);// 16384*512 bf16
  __hip_bfloat16* y_bf  = (__hip_bfloat16*)(ws + 25690112);   // 16384*512 bf16
  __hip_bfloat16* xs_bf = (__hip_bfloat16*)(ws + 29884416);   // 16384*512 bf16
  __hip_bfloat16* Atot  = (__hip_bfloat16*)(ws + 34078720);   // NCH*8192 bf16 (8.4MB)
  __hip_bfloat16* Btot  = (__hip_bfloat16*)(ws + 36175872);   // NCH*8192 bf16
  __hip_bfloat16* h0    = Btot;         // aliased (scan2 loads before store)
  __hip_bfloat16* inWt   = (__hip_bfloat16*)(ws + 42467328);  // 2*1024*256 bf16
  __hip_bfloat16* outWt  = (__hip_bfloat16*)(ws + 42729472);  // 2*256*512 bf16
  __hip_bfloat16* W1t    = (__hip_bfloat16*)(ws + 42860544);  // 128*256 bf16 (ln2g folded)
  __hip_bfloat16* Wdbc_t = (__hip_bfloat16*)(ws + 42876928);  // 2*640*512 bf16

  k_prep<<<5955,256,0,stream>>>(inW, rmsw, outW, W1, xpW, dtW, ln2g, ln2b, b1,
                                ln3g, ln3b, W2, b2, inWt, outWt, W1t, Wdbc_t,
                                rowsq1, rowsum2, rowsq2, mlp_pars);
  k_input<<<L_SEQ/4,256,0,stream>>>(x,Win,bin,ln1g,ln1b,u_bf,rowsq0);
  for(int i=0;i<2;i++){
    float* rsq_in = (i==0) ? rowsq0 : rowsq1;
    // in-proj with folded rms: xz = (u @ inWt') * rsqrt(rowsq/256+eps)
    k_mgemm<6,__hip_bfloat16><<<dim3(8, L_SEQ/128),512,0,stream>>>(
        u_bf, inWt+i*262144, nullptr, nullptr, xz_bf, nullptr, rsq_in, L_SEQ, DM, 1024, 1024);
    k_conv<<<(L_SEQ/CLB)*128/256,256,0,stream>>>(xz_bf, convW+i*DI*4, convB+i*DI, xs_bf);
    // merged delta|BC GEMM
    k_mgemm<4,__hip_bfloat16><<<dim3(5, L_SEQ/128),512,0,stream>>>(
        xs_bf, Wdbc_t+i*327680, dtB+i*DI, nullptr, delta_bf, dbc32, nullptr, L_SEQ, DI, 512, 544);
    k_scan1<<<NCH*2,256,0,stream>>>(delta_bf, xs_bf, dbc32, A_log+i*DI*DS, Atot, Btot);
    k_scan2<<<128,64,0,stream>>>(Atot, Btot, h0);
    k_scan3<<<NCH*2,256,0,stream>>>(delta_bf, xs_bf, dbc32, A_log+i*DI*DS, Dp+i*DI, h0, xz_bf, y_bf);
    if(i==0){
      k_mgemm<5,__hip_bfloat16><<<dim3(2, L_SEQ/128),512,0,stream>>>(
          y_bf, outWt, nullptr, u_bf, u_bf, nullptr, rowsq1, L_SEQ, DI, 256, 256);
    } else {
      // layer-1 out-proj: +R, write u, accumulate rowsum2/rowsq2 for folded LN2
      k_mgemm<7,__hip_bfloat16><<<dim3(2, L_SEQ/128),512,0,stream>>>(
          y_bf, outWt+131072, nullptr, u_bf, u_bf, rowsum2, rowsq2, L_SEQ, DI, 256, 256);
    }
  }
  // fused MLP: gelu(LN2(u)@W1+b1) -> LN3 -> @W2+b2 -> tanh -> out
  k_mgemm<8,float><<<dim3(1, L_SEQ/128),512,0,stream>>>(
      u_bf, W1t, nullptr, rowsum2, out, mlp_pars, rowsq2, L_SEQ, DM, 128, 128);
}

// Round 21
// 356.850 us; speedup vs baseline: 1.0217x; 1.0217x over previous
//
#include <hip/hip_runtime.h>
#include <hip/hip_bf16.h>
#include <math.h>

#define L_SEQ 16384
#define DM 256
#define DI 512
#define DS 16
#define NCH 512   // number of scan chunks
#define CHL 32    // chunk length (NCH*CHL == L_SEQ)
#define CLB 8     // conv: timesteps per thread

typedef __attribute__((ext_vector_type(8))) short short8v;
typedef __attribute__((ext_vector_type(4))) float f32x4;

__device__ __forceinline__ float tanh_fast(float x){
  float xc = fminf(x, 15.f);
  float t = __expf(2.f*xc);
  return (t-1.f)/(t+1.f);
}
__device__ __forceinline__ float gelu_f(float x){
  float x3 = x*x*x;
  return 0.5f*x*(1.0f + tanh_fast(0.7978845608028654f*(x + 0.044715f*x3)));
}
__device__ __forceinline__ float silu_f(float x){
  return x / (1.0f + __expf(-x));
}
__device__ __forceinline__ float softplus_f(float x){
  return fmaxf(x,0.0f) + __logf(1.0f + __expf(-fabsf(x)));
}
__device__ __forceinline__ float bf2f(unsigned short u){
  return __uint_as_float(((unsigned int)u)<<16);
}
__device__ __forceinline__ void gload16(const void* g, void* l){
  __builtin_amdgcn_global_load_lds((const __attribute__((address_space(1))) void*)g,
                                   (__attribute__((address_space(3))) void*)l, 16, 0, 0);
}

// r^(n+1) for n=0..15, ~16 muls, depth ~4 (replaces 16 quarter-rate exps)
__device__ __forceinline__ void powers16(float r, float* dA){
  float r2 = r*r;
  float r4 = r2*r2;
  float r8 = r4*r4;
  dA[0]=r;        dA[1]=r2;       dA[2]=r2*r;     dA[3]=r4;
  dA[4]=r4*r;     dA[5]=r4*r2;    dA[6]=r4*dA[2]; dA[7]=r8;
  dA[8]=r8*r;     dA[9]=r8*r2;    dA[10]=r8*dA[2];dA[11]=r8*r4;
  dA[12]=r8*dA[4];dA[13]=r8*dA[5];dA[14]=r8*dA[6];dA[15]=r8*r8;
}

// ---- merged weight prep (rmsw->inWt, ln2g->W1t) + zeros + MLP par table.
//      pars: [0:128) gW1s  [128:256) bW1s+b1  [256:384) ln3g  [384:512) ln3b
//            [512:640) W2  [640] b2 ----
__global__ void k_prep(const float* __restrict__ inW, const float* __restrict__ rmsw,
                       const float* __restrict__ outW, const float* __restrict__ W1,
                       const float* __restrict__ xpW, const float* __restrict__ dtW,
                       const float* __restrict__ ln2g, const float* __restrict__ ln2b,
                       const float* __restrict__ b1, const float* __restrict__ ln3g,
                       const float* __restrict__ ln3b, const float* __restrict__ W2,
                       const float* __restrict__ b2,
                       __hip_bfloat16* __restrict__ inWt, __hip_bfloat16* __restrict__ outWt,
                       __hip_bfloat16* __restrict__ W1t, __hip_bfloat16* __restrict__ Wdbc_t,
                       float* __restrict__ rowsq1, float* __restrict__ rowsum2,
                       float* __restrict__ rowsq2, float* __restrict__ pars){
  int idx = blockIdx.x*256 + threadIdx.x;
  if(idx < 524288){                      // inW: 2x[256][1024] -> [1024][256], rmsw fold
    int layer = idx >> 18;
    int r = idx & 262143;
    int n = r >> 8, k = r & 255;
    inWt[idx] = __float2bfloat16(inW[layer*262144 + k*1024 + n] * rmsw[layer*256+k]);
  } else if(idx < 786432){               // outW: 2x[512][256] -> [256][512]
    int j = idx - 524288;
    int layer = j >> 17;
    int r = j & 131071;
    int n = r >> 9, k = r & 511;
    outWt[j] = __float2bfloat16(outW[layer*131072 + k*256 + n]);
  } else if(idx < 819200){               // W1: [256][128] -> [128][256], ln2g fold
    int j = idx - 786432;
    int n = j >> 8, k = j & 255;
    W1t[j] = __float2bfloat16(W1[k*128 + n] * ln2g[k]);
  } else if(idx < 1474560){              // Wdbc: 2x[640][512]
    int j = idx - 819200;
    int layer = j / 327680;
    int r = j % 327680;
    int n = r >> 9, k = r & 511;
    const float* xp = xpW + layer*512*48;
    float v;
    if(n < 512){
      const float* dt = dtW + layer*16*512;
      float s = 0.f;
#pragma unroll
      for(int q=0;q<16;q++) s = fmaf(xp[k*48+q], dt[q*512+n], s);
      v = s;
    } else if(n < 544){
      v = xp[k*48 + 16 + (n-512)];
    } else v = 0.f;
    Wdbc_t[j] = __float2bfloat16(v);
  } else if(idx < 1490944){              // rowsq1 zero
    rowsq1[idx - 1474560] = 0.f;
  } else if(idx < 1507328){              // rowsum2 zero
    rowsum2[idx - 1490944] = 0.f;
  } else if(idx < 1523712){              // rowsq2 zero
    rowsq2[idx - 1507328] = 0.f;
  } else if(idx < 1524353){              // MLP par table
    int j = idx - 1523712;
    if(j < 128){
      float s = 0.f;
      for(int k=0;k<256;k++) s = fmaf(ln2g[k], W1[k*128+j], s);
      pars[j] = s;
    } else if(j < 256){
      int n = j - 128;
      float s = 0.f;
      for(int k=0;k<256;k++) s = fmaf(ln2b[k], W1[k*128+n], s);
      pars[j] = s + b1[n];
    } else if(j < 384) pars[j] = ln3g[j-256];
    else if(j < 512)   pars[j] = ln3b[j-384];
    else if(j < 640)   pars[j] = W2[j-512];
    else               pars[640] = b2[0];
  }
}

// ---- input projection + LN + gelu -> bf16 u; also rowsq0[r] = sum(u_r^2) ----
__global__ __launch_bounds__(256) void k_input(const float* __restrict__ x,
                        const float* __restrict__ Win, const float* __restrict__ bin,
                        const float* __restrict__ g, const float* __restrict__ b,
                        __hip_bfloat16* __restrict__ u, float* __restrict__ rowsq){
  int wv = threadIdx.x>>6, lane = threadIdx.x&63;
  int r = blockIdx.x*4 + wv;
  int c0 = lane*4;
  float acc[4];
  { float4 bv = *(const float4*)&bin[c0];
    acc[0]=bv.x; acc[1]=bv.y; acc[2]=bv.z; acc[3]=bv.w; }
#pragma unroll
  for(int k=0;k<32;k++){
    float xk = x[r*32+k];
    float4 wv4 = *(const float4*)&Win[k*DM+c0];
    acc[0]=fmaf(xk,wv4.x,acc[0]); acc[1]=fmaf(xk,wv4.y,acc[1]);
    acc[2]=fmaf(xk,wv4.z,acc[2]); acc[3]=fmaf(xk,wv4.w,acc[3]);
  }
  float s = (acc[0]+acc[1])+(acc[2]+acc[3]);
  float sq = acc[0]*acc[0]+acc[1]*acc[1]+acc[2]*acc[2]+acc[3]*acc[3];
#pragma unroll
  for(int o=32;o;o>>=1){ s += __shfl_xor(s,o); sq += __shfl_xor(sq,o); }
  float mean = s*(1.0f/DM);
  float var = sq*(1.0f/DM) - mean*mean;
  float rs = rsqrtf(var+1e-5f);
  float4 gv = *(const float4*)&g[c0];
  float4 bv = *(const float4*)&b[c0];
  float go[4];
  go[0] = gelu_f((acc[0]-mean)*rs*gv.x+bv.x);
  go[1] = gelu_f((acc[1]-mean)*rs*gv.y+bv.y);
  go[2] = gelu_f((acc[2]-mean)*rs*gv.z+bv.z);
  go[3] = gelu_f((acc[3]-mean)*rs*gv.w+bv.w);
  float ssq = go[0]*go[0]+go[1]*go[1]+go[2]*go[2]+go[3]*go[3];
#pragma unroll
  for(int o=32;o;o>>=1) ssq += __shfl_xor(ssq,o);
  if(lane==0) rowsq[r] = ssq;
  __hip_bfloat16 ob[4] = {__float2bfloat16(go[0]),__float2bfloat16(go[1]),
                          __float2bfloat16(go[2]),__float2bfloat16(go[3])};
  *(uint2*)&u[r*DM+c0] = *(uint2*)ob;
}

// ---- bf16 MFMA GEMM, 8 waves, BK=64 DOUBLE-BUFFERED (counted vmcnt(4)) +
//      XCD remap + two-half LDS-staged coalesced epilogue.
//      EPI: 0=store, 1=+R, 4=delta|BC split, 5=+R+rowsq atomic,
//      6=row-scale rsqrt(rowsq/256+eps), 7=+R+rowsum&rowsq atomics,
//      8=MLP fused: LN2-folded gelu + LN3 + W2 dot + tanh -> C[row]. ----
template<int EPI, typename OT>
__global__ __launch_bounds__(512) void k_mgemm(const __hip_bfloat16* __restrict__ A,
    const __hip_bfloat16* __restrict__ Wt, const float* __restrict__ bias,
    const OT* __restrict__ R, OT* __restrict__ C, float* __restrict__ C2,
    float* __restrict__ rowsq, int M, int K, int ldc, int Nout){
  __shared__ char lds[66560];          // As0|As1|Bs0|Bs1 16KB each; Ob[64][132] overlays
  float* Ob = (float*)lds;             // [64][132] f32 (33.8KB), reused post-compute
  int t = threadIdx.x, lane = t&63, wave = t>>6;   // 8 waves
  // XCD-aware tile remap (block f -> XCD f%8; XCD owns contiguous y-panels)
  int gx = gridDim.x;
  int f = blockIdx.y*gx + blockIdx.x;
  int s = f >> 3;
  int sy = s/gx;
  int yb = (f&7)*(gridDim.y>>3) + sy;
  int xb = s - sy*gx;
  int m0 = yb*128, n0 = xb*128;
  int wm = (wave>>1)*32, wn = (wave&1)*64;   // wave owns 32 rows x 64 cols
  f32x4 acc[2][4] = {};
  // staging descriptors (BK=64: 128B rows, 8-slot XOR swizzle)
  int soff[2], srow[2], scol[2];
#pragma unroll
  for(int c=0;c<2;c++){
    int off = c*8192 + t*16;
    int row = off>>7;
    int sl  = ((off>>4)&7) ^ (row&7);
    soff[c]=off; srow[c]=row; scol[c]=sl*8;
  }
  int nk = K >> 6;
  // prologue: stage tile 0 into buffer 0
#pragma unroll
  for(int c=0;c<2;c++){
    gload16(&A [(m0+srow[c])*K + scol[c]], lds + soff[c]);
    gload16(&Wt[(n0+srow[c])*K + scol[c]], lds + 32768 + soff[c]);
  }
  for(int ki=0; ki<nk; ki++){
    int co = (ki & 1) ? 16384 : 0;       // current buffer byte offset
    if(ki+1 < nk){
      int no = co ^ 16384;
      int kt = (ki+1)<<6;
#pragma unroll
      for(int c=0;c<2;c++){
        gload16(&A [(m0+srow[c])*K + kt + scol[c]], lds + no + soff[c]);
        gload16(&Wt[(n0+srow[c])*K + kt + scol[c]], lds + 32768 + no + soff[c]);
      }
      asm volatile("s_waitcnt vmcnt(4)" ::: "memory");  // tile ki landed, next 4 in flight
    } else {
      asm volatile("s_waitcnt vmcnt(0)" ::: "memory");
    }
    __builtin_amdgcn_s_barrier();
    asm volatile("" ::: "memory");
    const short* As = (const short*)(lds + co);
    const short* Bs = (const short*)(lds + 32768 + co);
#pragma unroll
    for(int ks=0; ks<2; ks++){
      short8v a[2], b[4];
      int k8 = ks*4 + (lane>>4);
#pragma unroll
      for(int i=0;i<2;i++){
        int lr = wm + i*16 + (lane&15);
        a[i] = *(const short8v*)&As[lr*64 + (k8 ^ (lr&7))*8];
      }
#pragma unroll
      for(int j=0;j<4;j++){
        int lr = wn + j*16 + (lane&15);
        b[j] = *(const short8v*)&Bs[lr*64 + (k8 ^ (lr&7))*8];
      }
#pragma unroll
      for(int i=0;i<2;i++)
#pragma unroll
        for(int j=0;j<4;j++)
          acc[i][j] = __builtin_amdgcn_mfma_f32_16x16x32_bf16(a[i], b[j], acc[i][j], 0,0,0);
    }
    asm volatile("" ::: "memory");
    __builtin_amdgcn_s_barrier();   // all reads of buf[cur] done before its restage
  }
  // two-half epilogue: rows [h*64, h*64+64)
#pragma unroll
  for(int h=0; h<2; h++){
    __syncthreads();
    if((wm>>6)==h){
      int base = wm & 63;
#pragma unroll
      for(int i=0;i<2;i++)
#pragma unroll
        for(int j=0;j<4;j++)
#pragma unroll
          for(int r=0;r<4;r++)
            Ob[(base + i*16 + (lane>>4)*4 + r)*132 + wn + j*16 + (lane&15)] = acc[i][j][r];
    }
    __syncthreads();
    if constexpr(EPI==8){
      // LN2-folded MLP + LN3 + W2 + tanh. 8 threads per row, 16 cols each.
      int rl = t>>3;
      int grow = m0 + h*64 + rl;
      int c0b = (t&7)*16;
      float mean = (float)R[grow]*(1.0f/DM);
      float var = rowsq[grow]*(1.0f/DM) - mean*mean;
      float rsv = rsqrtf(var+1e-5f);
      float hbuf[16];
      float s3=0.f, q3=0.f;
#pragma unroll
      for(int v=0;v<4;v++){
        float4 o = *(const float4*)&Ob[rl*132 + c0b + v*4];
        float oa[4] = {o.x,o.y,o.z,o.w};
#pragma unroll
        for(int j=0;j<4;j++){
          int col = c0b + v*4 + j;
          float val = rsv*oa[j] - rsv*mean*C2[col] + C2[128+col];
          float hh = gelu_f(val);
          hbuf[v*4+j] = hh;
          s3 += hh; q3 += hh*hh;
        }
      }
      s3 += __shfl_xor(s3,1); q3 += __shfl_xor(q3,1);
      s3 += __shfl_xor(s3,2); q3 += __shfl_xor(q3,2);
      s3 += __shfl_xor(s3,4); q3 += __shfl_xor(q3,4);
      float m3 = s3*(1.0f/128), v3 = q3*(1.0f/128) - m3*m3;
      float rs3 = rsqrtf(v3+1e-5f);
      float dot = 0.f;
#pragma unroll
      for(int j=0;j<16;j++){
        int col = c0b + j;
        dot += ((hbuf[j]-m3)*rs3*C2[256+col] + C2[384+col]) * C2[512+col];
      }
      dot += __shfl_xor(dot,1); dot += __shfl_xor(dot,2); dot += __shfl_xor(dot,4);
      if((t&7)==0) C[grow] = tanh_fast(dot + C2[640]);
    } else {
      float ssq_acc = 0.f, ssum_acc = 0.f;
#pragma unroll
      for(int v=0; v<4; v++){
        int fidx = (t*4+v)*4;
        int row = fidx>>7, col = fidx&127;
        if(col < Nout){
          float4 o = *(const float4*)&Ob[row*132 + col];
          int grow = m0 + h*64 + row, gcol = n0 + col;
          if(EPI==1 || EPI==5 || EPI==7){
            if constexpr(sizeof(OT)==2){
              ushort4 rv = *(const ushort4*)&R[grow*ldc+gcol];
              o.x+=bf2f(rv.x); o.y+=bf2f(rv.y); o.z+=bf2f(rv.z); o.w+=bf2f(rv.w);
            } else {
              float4 rv = *(const float4*)&R[grow*ldc+gcol];
              o.x+=rv.x; o.y+=rv.y; o.z+=rv.z; o.w+=rv.w;
            }
            if(EPI==5 || EPI==7) ssq_acc += o.x*o.x + o.y*o.y + o.z*o.z + o.w*o.w;
            if(EPI==7) ssum_acc += o.x + o.y + o.z + o.w;
          }
          if(EPI==6){
            float rs = rsqrtf(rowsq[grow]*(1.0f/DM) + 1e-5f);
            o.x*=rs; o.y*=rs; o.z*=rs; o.w*=rs;
          }
          if(EPI==4){
            if(gcol < 512){
              float4 bv = *(const float4*)&bias[gcol];
              float4 so = {softplus_f(o.x+bv.x), softplus_f(o.y+bv.y),
                           softplus_f(o.z+bv.z), softplus_f(o.w+bv.w)};
              __hip_bfloat16 ob[4] = {__float2bfloat16(so.x),__float2bfloat16(so.y),
                                      __float2bfloat16(so.z),__float2bfloat16(so.w)};
              *(uint2*)&C[grow*ldc+gcol] = *(uint2*)ob;
            } else {
              *(float4*)&C2[grow*32 + (gcol-512)] = o;
            }
          } else {
            if constexpr(sizeof(OT)==2){
              __hip_bfloat16 ob[4] = {__float2bfloat16(o.x),__float2bfloat16(o.y),
                                      __float2bfloat16(o.z),__float2bfloat16(o.w)};
              *(uint2*)&C[grow*ldc+gcol] = *(uint2*)ob;
            } else {
              *(float4*)&C[grow*ldc+gcol] = o;
            }
          }
        }
      }
      if(EPI==5 || EPI==7){
        ssq_acc += __shfl_xor(ssq_acc,1);
        ssq_acc += __shfl_xor(ssq_acc,2);
        ssq_acc += __shfl_xor(ssq_acc,4);
        if((t&7)==0) atomicAdd(&rowsq[m0 + h*64 + (t>>3)], ssq_acc);
      }
      if(EPI==7){
        ssum_acc += __shfl_xor(ssum_acc,1);
        ssum_acc += __shfl_xor(ssum_acc,2);
        ssum_acc += __shfl_xor(ssum_acc,4);
        if((t&7)==0) atomicAdd(&C2[m0 + h*64 + (t>>3)], ssum_acc);
      }
    }
  }
}

// ---- causal depthwise conv (k=4) + bias + silu, sliding window. ----
__global__ __launch_bounds__(256) void k_conv(const __hip_bfloat16* __restrict__ xz,
                       const float* __restrict__ cw, const float* __restrict__ cb,
                       __hip_bfloat16* __restrict__ xs_bf){
  int idx = blockIdx.x*256 + threadIdx.x;   // (L_SEQ/CLB)*128 threads
  int cg = idx & 127, lb = idx >> 7;
  int c4 = cg*4;
  int l0 = lb*CLB;
  float w[4][4], bias[4];
#pragma unroll
  for(int j=0;j<4;j++){
    float4 wv = *(const float4*)&cw[(c4+j)*4];
    w[j][0]=wv.x; w[j][1]=wv.y; w[j][2]=wv.z; w[j][3]=wv.w;
  }
  { float4 bv = *(const float4*)&cb[c4];
    bias[0]=bv.x; bias[1]=bv.y; bias[2]=bv.z; bias[3]=bv.w; }
  float xm0[4], xm1[4], xm2[4];   // x[l-3], x[l-2], x[l-1]
#pragma unroll
  for(int j=0;j<4;j++){ xm0[j]=0.f; xm1[j]=0.f; xm2[j]=0.f; }
  if(l0 >= 3){
    ushort4 r0 = *(const ushort4*)&xz[(l0-3)*1024 + c4];
    ushort4 r1 = *(const ushort4*)&xz[(l0-2)*1024 + c4];
    ushort4 r2 = *(const ushort4*)&xz[(l0-1)*1024 + c4];
    xm0[0]=bf2f(r0.x); xm0[1]=bf2f(r0.y); xm0[2]=bf2f(r0.z); xm0[3]=bf2f(r0.w);
    xm1[0]=bf2f(r1.x); xm1[1]=bf2f(r1.y); xm1[2]=bf2f(r1.z); xm1[3]=bf2f(r1.w);
    xm2[0]=bf2f(r2.x); xm2[1]=bf2f(r2.y); xm2[2]=bf2f(r2.z); xm2[3]=bf2f(r2.w);
  }
#pragma unroll 4
  for(int l=l0; l<l0+CLB; l++){
    ushort4 rc = *(const ushort4*)&xz[l*1024 + c4];
    float xc[4] = {bf2f(rc.x), bf2f(rc.y), bf2f(rc.z), bf2f(rc.w)};
    __hip_bfloat16 ob[4];
#pragma unroll
    for(int j=0;j<4;j++){
      float acc = bias[j];
      acc = fmaf(xm0[j], w[j][0], acc);
      acc = fmaf(xm1[j], w[j][1], acc);
      acc = fmaf(xm2[j], w[j][2], acc);
      acc = fmaf(xc[j],  w[j][3], acc);
      ob[j] = __float2bfloat16(silu_f(acc));
    }
    *(uint2*)&xs_bf[l*DI + c4] = *(uint2*)ob;
#pragma unroll
    for(int j=0;j<4;j++){ xm0[j]=xm1[j]; xm1[j]=xm2[j]; xm2[j]=xc[j]; }
  }
}

// ---- scan phase 1: per-chunk (prod dA, local carry) per state -> bf16.
//      Fast path: A[n] == (n+1)*A[0] -> dA[n] = r^(n+1), r = exp(d*A[0]). ----
__global__ __launch_bounds__(256) void k_scan1(const __hip_bfloat16* __restrict__ delta,
                        const __hip_bfloat16* __restrict__ xs,
                        const float* __restrict__ dbc32, const float* __restrict__ A_log,
                        __hip_bfloat16* __restrict__ Atot, __hip_bfloat16* __restrict__ Btot){
  __shared__ float bcs[CHL*32];
  int t = threadIdx.x;
  int chunk = blockIdx.x >> 1;
  int e = ((blockIdx.x & 1) << 8) + t;
  int l0 = chunk*CHL;
  ((float4*)bcs)[t] = ((const float4*)&dbc32[l0*32])[t];
  float A[16];
  {
    const float4* al = (const float4*)&A_log[e*DS];
#pragma unroll
    for(int q=0;q<4;q++){
      float4 a = al[q];
      A[q*4+0] = -__expf(a.x); A[q*4+1] = -__expf(a.y);
      A[q*4+2] = -__expf(a.z); A[q*4+3] = -__expf(a.w);
    }
  }
  bool pf = true;
#pragma unroll
  for(int n=1;n<16;n++) pf = pf && (fabsf(A[n] - (n+1)*A[0]) <= 1e-4f*fabsf(A[n]));
  float carry[16], aprod[16];
#pragma unroll
  for(int n=0;n<16;n++){ carry[n]=0.f; aprod[n]=1.f; }
  __syncthreads();
  if(pf){
    float A0 = A[0];
#pragma unroll 2
    for(int li=0; li<CHL; li++){
      int l = l0 + li;
      float d  = bf2f(*(const unsigned short*)&delta[l*DI+e]);
      float xv = bf2f(*(const unsigned short*)&xs[l*DI+e]);
      float dxv = d*xv;
      const float4* bp = (const float4*)&bcs[li*32];
      float4 b0=bp[0], b1=bp[1], b2=bp[2], b3=bp[3];
      float B[16] = {b0.x,b0.y,b0.z,b0.w, b1.x,b1.y,b1.z,b1.w,
                     b2.x,b2.y,b2.z,b2.w, b3.x,b3.y,b3.z,b3.w};
      float r = __expf(d*A0);
      float dA[16]; powers16(r, dA);
#pragma unroll
      for(int n=0;n<16;n++){
        carry[n] = fmaf(carry[n], dA[n], dxv*B[n]);
        aprod[n] *= dA[n];
      }
    }
  } else {
#pragma unroll 2
    for(int li=0; li<CHL; li++){
      int l = l0 + li;
      float d  = bf2f(*(const unsigned short*)&delta[l*DI+e]);
      float xv = bf2f(*(const unsigned short*)&xs[l*DI+e]);
      float dxv = d*xv;
      const float4* bp = (const float4*)&bcs[li*32];
      float4 b0=bp[0], b1=bp[1], b2=bp[2], b3=bp[3];
      float B[16] = {b0.x,b0.y,b0.z,b0.w, b1.x,b1.y,b1.z,b1.w,
                     b2.x,b2.y,b2.z,b2.w, b3.x,b3.y,b3.z,b3.w};
#pragma unroll
      for(int n=0;n<16;n++){
        float dA = __expf(d*A[n]);
        carry[n] = fmaf(carry[n], dA, dxv*B[n]);
        aprod[n] *= dA;
      }
    }
  }
  __hip_bfloat16 apk[16], bpk[16];
#pragma unroll
  for(int n=0;n<16;n++){
    apk[n] = __float2bfloat16(aprod[n]);
    bpk[n] = __float2bfloat16(carry[n]);
  }
  uint4* ap = (uint4*)&Atot[chunk*8192 + e*DS];
  uint4* bp = (uint4*)&Btot[chunk*8192 + e*DS];
  ap[0] = ((const uint4*)apk)[0]; ap[1] = ((const uint4*)apk)[1];
  bp[0] = ((const uint4*)bpk)[0]; bp[1] = ((const uint4*)bpk)[1];
}

// ---- scan phase 2: carry-in per chunk (bf16 in/out), unroll-8 batched loads
//      (h0 aliases Btot: all batch loads precede batch stores). 128 blocks x 64. ----
__global__ __launch_bounds__(64) void k_scan2(const __hip_bfloat16* __restrict__ Atot,
                        const __hip_bfloat16* __restrict__ Btot,
                        __hip_bfloat16* __restrict__ h0){
  int tg = blockIdx.x*64 + threadIdx.x;
  float carry = 0.f;
  for(int c0=0;c0<NCH;c0+=8){
    float a[8], b[8];
#pragma unroll
    for(int j=0;j<8;j++){
      a[j] = bf2f(*(const unsigned short*)&Atot[(c0+j)*8192+tg]);
      b[j] = bf2f(*(const unsigned short*)&Btot[(c0+j)*8192+tg]);
    }
#pragma unroll
    for(int j=0;j<8;j++){
      h0[(c0+j)*8192+tg] = __float2bfloat16(carry);
      carry = fmaf(carry, a[j], b[j]);
    }
  }
}

// ---- scan phase 3: replay with bf16 carry-in, y = (sum h*C + xs*D)*silu(z) -> bf16 ----
__global__ __launch_bounds__(256) void k_scan3(const __hip_bfloat16* __restrict__ delta,
                        const __hip_bfloat16* __restrict__ xs,
                        const float* __restrict__ dbc32, const float* __restrict__ A_log,
                        const float* __restrict__ Dp, const __hip_bfloat16* __restrict__ h0,
                        const __hip_bfloat16* __restrict__ xz, __hip_bfloat16* __restrict__ y){
  __shared__ float bcs[CHL*32];
  int t = threadIdx.x;
  int chunk = blockIdx.x >> 1;
  int e = ((blockIdx.x & 1) << 8) + t;
  int l0 = chunk*CHL;
  ((float4*)bcs)[t] = ((const float4*)&dbc32[l0*32])[t];
  float A[16];
  {
    const float4* al = (const float4*)&A_log[e*DS];
#pragma unroll
    for(int q=0;q<4;q++){
      float4 a = al[q];
      A[q*4+0] = -__expf(a.x); A[q*4+1] = -__expf(a.y);
      A[q*4+2] = -__expf(a.z); A[q*4+3] = -__expf(a.w);
    }
  }
  bool pf = true;
#pragma unroll
  for(int n=1;n<16;n++) pf = pf && (fabsf(A[n] - (n+1)*A[0]) <= 1e-4f*fabsf(A[n]));
  float carry[16];
  {
    uint4 h0a = ((const uint4*)&h0[chunk*8192 + e*DS])[0];
    uint4 h0b = ((const uint4*)&h0[chunk*8192 + e*DS])[1];
    const unsigned short* hp = (const unsigned short*)&h0a;
#pragma unroll
    for(int n=0;n<8;n++) carry[n] = bf2f(hp[n]);
    const unsigned short* hq = (const unsigned short*)&h0b;
#pragma unroll
    for(int n=0;n<8;n++) carry[8+n] = bf2f(hq[n]);
  }
  float Dv = Dp[e];
  __syncthreads();
  if(pf){
    float A0 = A[0];
#pragma unroll 2
    for(int li=0; li<CHL; li++){
      int l = l0 + li;
      float d  = bf2f(*(const unsigned short*)&delta[l*DI+e]);
      float xv = bf2f(*(const unsigned short*)&xs[l*DI+e]);
      float dxv = d*xv;
      const float4* bp = (const float4*)&bcs[li*32];
      float4 b0=bp[0], b1=bp[1], b2=bp[2], b3=bp[3];
      float4 c0=bp[4], c1=bp[5], c2=bp[6], c3=bp[7];
      float B[16] = {b0.x,b0.y,b0.z,b0.w, b1.x,b1.y,b1.z,b1.w,
                     b2.x,b2.y,b2.z,b2.w, b3.x,b3.y,b3.z,b3.w};
      float Cv[16] = {c0.x,c0.y,c0.z,c0.w, c1.x,c1.y,c1.z,c1.w,
                      c2.x,c2.y,c2.z,c2.w, c3.x,c3.y,c3.z,c3.w};
      float r = __expf(d*A0);
      float dA[16]; powers16(r, dA);
      float p[4] = {0.f,0.f,0.f,0.f};
#pragma unroll
      for(int n=0;n<16;n++){
        carry[n] = fmaf(carry[n], dA[n], dxv*B[n]);
        p[n&3] = fmaf(carry[n], Cv[n], p[n&3]);
      }
      float ps = (p[0]+p[1]) + (p[2]+p[3]);
      float z = bf2f(*(const unsigned short*)&xz[l*1024 + 512 + e]);
      y[l*DI+e] = __float2bfloat16(fmaf(xv, Dv, ps) * silu_f(z));
    }
  } else {
#pragma unroll 2
    for(int li=0; li<CHL; li++){
      int l = l0 + li;
      float d  = bf2f(*(const unsigned short*)&delta[l*DI+e]);
      float xv = bf2f(*(const unsigned short*)&xs[l*DI+e]);
      float dxv = d*xv;
      const float4* bp = (const float4*)&bcs[li*32];
      float4 b0=bp[0], b1=bp[1], b2=bp[2], b3=bp[3];
      float4 c0=bp[4], c1=bp[5], c2=bp[6], c3=bp[7];
      float B[16] = {b0.x,b0.y,b0.z,b0.w, b1.x,b1.y,b1.z,b1.w,
                     b2.x,b2.y,b2.z,b2.w, b3.x,b3.y,b3.z,b3.w};
      float Cv[16] = {c0.x,c0.y,c0.z,c0.w, c1.x,c1.y,c1.z,c1.w,
                      c2.x,c2.y,c2.z,c2.w, c3.x,c3.y,c3.z,c3.w};
      float p[4] = {0.f,0.f,0.f,0.f};
#pragma unroll
      for(int n=0;n<16;n++){
        float dA = __expf(d*A[n]);
        carry[n] = fmaf(carry[n], dA, dxv*B[n]);
        p[n&3] = fmaf(carry[n], Cv[n], p[n&3]);
      }
      float ps = (p[0]+p[1]) + (p[2]+p[3]);
      float z = bf2f(*(const unsigned short*)&xz[l*1024 + 512 + e]);
      y[l*DI+e] = __float2bfloat16(fmaf(xv, Dv, ps) * silu_f(z));
    }
  }
}

extern "C" void kernel_launch(void* const* d_in, const int* in_sizes, int n_in,
                              void* d_out, int out_size, void* d_ws, size_t ws_size,
                              hipStream_t stream){
  const float* x    = (const float*)d_in[0];
  const float* Win  = (const float*)d_in[1];
  const float* bin  = (const float*)d_in[2];
  const float* ln1g = (const float*)d_in[3];
  const float* ln1b = (const float*)d_in[4];
  const float* rmsw = (const float*)d_in[5];
  const float* inW  = (const float*)d_in[6];
  const float* convW= (const float*)d_in[7];
  const float* convB= (const float*)d_in[8];
  const float* xpW  = (const float*)d_in[9];
  const float* dtW  = (const float*)d_in[10];
  const float* dtB  = (const float*)d_in[11];
  const float* A_log= (const float*)d_in[12];
  const float* Dp   = (const float*)d_in[13];
  const float* outW = (const float*)d_in[14];
  const float* ln2g = (const float*)d_in[15];
  const float* ln2b = (const float*)d_in[16];
  const float* W1   = (const float*)d_in[17];
  const float* b1   = (const float*)d_in[18];
  const float* ln3g = (const float*)d_in[19];
  const float* ln3b = (const float*)d_in[20];
  const float* W2   = (const float*)d_in[21];
  const float* b2   = (const float*)d_in[22];
  float* out = (float*)d_out;
  float* ws = (float*)d_ws;
  __hip_bfloat16* u_bf = (__hip_bfloat16*)ws;                 // 16384*256 bf16 (8MB)
  float* rowsq0  = ws + 4194304;                              // 16384 f32
  float* rowsq1  = ws + 4210688;                              // 16384 f32
  float* rowsum2 = ws + 4227072;                              // 16384 f32
  float* rowsq2  = ws + 4243456;                              // 16384 f32
  float* mlp_pars= ws + 4259840;                              // 641 f32
  __hip_bfloat16* xz_bf = (__hip_bfloat16*)(ws + 8388608);    // 16384*1024 bf16
  float* dbc32 = ws + 16777216;                               // 16384*32 f32
  __hip_bfloat16* delta_bf = (__hip_bfloat16*)(ws + 17301504);// 16384*512 bf16
  __hip_bfloat16* y_bf  = (__hip_bfloat16*)(ws + 25690112);   // 16384*512 bf16
  __hip_bfloat16* xs_bf = (__hip_bfloat16*)(ws + 29884416);   // 16384*512 bf16
  __hip_bfloat16* Atot  = (__hip_bfloat16*)(ws + 34078720);   // NCH*8192 bf16 (8.4MB)
  __hip_bfloat16* Btot  = (__hip_bfloat16*)(ws + 36175872);   // NCH*8192 bf16
  __hip_bfloat16* h0    = Btot;         // aliased (scan2 loads before store)
  __hip_bfloat16* inWt   = (__hip_bfloat16*)(ws + 42467328);  // 2*1024*256 bf16
  __hip_bfloat16* outWt  = (__hip_bfloat16*)(ws + 42729472);  // 2*256*512 bf16
  __hip_bfloat16* W1t    = (__hip_bfloat16*)(ws + 42860544);  // 128*256 bf16 (ln2g folded)
  __hip_bfloat16* Wdbc_t = (__hip_bfloat16*)(ws + 42876928);  // 2*640*512 bf16

  k_prep<<<5955,256,0,stream>>>(inW, rmsw, outW, W1, xpW, dtW, ln2g, ln2b, b1,
                                ln3g, ln3b, W2, b2, inWt, outWt, W1t, Wdbc_t,
                                rowsq1, rowsum2, rowsq2, mlp_pars);
  k_input<<<L_SEQ/4,256,0,stream>>>(x,Win,bin,ln1g,ln1b,u_bf,rowsq0);
  for(int i=0;i<2;i++){
    float* rsq_in = (i==0) ? rowsq0 : rowsq1;
    // in-proj with folded rms: xz = (u @ inWt') * rsqrt(rowsq/256+eps)
    k_mgemm<6,__hip_bfloat16><<<dim3(8, L_SEQ/128),512,0,stream>>>(
        u_bf, inWt+i*262144, nullptr, nullptr, xz_bf, nullptr, rsq_in, L_SEQ, DM, 1024, 1024);
    k_conv<<<(L_SEQ/CLB)*128/256,256,0,stream>>>(xz_bf, convW+i*DI*4, convB+i*DI, xs_bf);
    // merged delta|BC GEMM
    k_mgemm<4,__hip_bfloat16><<<dim3(5, L_SEQ/128),512,0,stream>>>(
        xs_bf, Wdbc_t+i*327680, dtB+i*DI, nullptr, delta_bf, dbc32, nullptr, L_SEQ, DI, 512, 544);
    k_scan1<<<NCH*2,256,0,stream>>>(delta_bf, xs_bf, dbc32, A_log+i*DI*DS, Atot, Btot);
    k_scan2<<<128,64,0,stream>>>(Atot, Btot, h0);
    k_scan3<<<NCH*2,256,0,stream>>>(delta_bf, xs_bf, dbc32, A_log+i*DI*DS, Dp+i*DI, h0, xz_bf, y_bf);
    if(i==0){
      k_mgemm<5,__hip_bfloat16><<<dim3(2, L_SEQ/128),512,0,stream>>>(
          y_bf, outWt, nullptr, u_bf, u_bf, nullptr, rowsq1, L_SEQ, DI, 256, 256);
    } else {
      // layer-1 out-proj: +R, write u, accumulate rowsum2/rowsq2 for folded LN2
      k_mgemm<7,__hip_bfloat16><<<dim3(2, L_SEQ/128),512,0,stream>>>(
          y_bf, outWt+131072, nullptr, u_bf, u_bf, rowsum2, rowsq2, L_SEQ, DI, 256, 256);
    }
  }
  // fused MLP: gelu(LN2(u)@W1+b1) -> LN3 -> @W2+b2 -> tanh -> out
  k_mgemm<8,float><<<dim3(1, L_SEQ/128),512,0,stream>>>(
      u_bf, W1t, nullptr, rowsum2, out, mlp_pars, rowsq2, L_SEQ, DM, 128, 128);
}